// Round 1
// baseline (1208.179 us; speedup 1.0000x reference)
//
#include <hip/hip_runtime.h>

// ---------------------------------------------------------------------------
// GraphSAGE (3x SAGEConv mean-agg + BN/ReLU) + link decoder, all f32.
// Strategy:
//  - linear commutes with mean: transform nodes first, aggregate 128-wide
//  - CSR built on device once per launch (count/scan/scatter), gather-sum agg
//  - decoder: relu(z_s@Wa + z_d@Wb + b) . w2  with u=z@Wa, v=z@Wb per-node
// ---------------------------------------------------------------------------

__global__ void count_kernel(const int* __restrict__ dst, int* __restrict__ cnt, int E) {
    int i = blockIdx.x * blockDim.x + threadIdx.x;
    if (i < E) atomicAdd(&cnt[dst[i]], 1);
}

__global__ void scan_kernel(const int* __restrict__ cnt, int* __restrict__ ptr, int n) {
    __shared__ int sd[1024];
    int t = threadIdx.x;
    int running = 0;
    for (int base = 0; base < n; base += 1024) {
        int i = base + t;
        int v = (i < n) ? cnt[i] : 0;
        sd[t] = v;
        __syncthreads();
        #pragma unroll
        for (int off = 1; off < 1024; off <<= 1) {
            int add = (t >= off) ? sd[t - off] : 0;
            __syncthreads();
            sd[t] += add;
            __syncthreads();
        }
        if (i < n) ptr[i] = running + sd[t] - v;   // exclusive scan
        running += sd[1023];
        __syncthreads();
    }
    if (t == 0) ptr[n] = running;
}

__global__ void scatter_kernel(const int* __restrict__ src, const int* __restrict__ dst,
                               const int* __restrict__ ptr, int* __restrict__ cursor,
                               int* __restrict__ edges, int E) {
    int i = blockIdx.x * blockDim.x + threadIdx.x;
    if (i < E) {
        int d = dst[i];
        int pos = ptr[d] + atomicAdd(&cursor[d], 1);
        edges[pos] = src[i];
    }
}

// C[n][128] (tile m0 = blockIdx.y*64) = A[n][K] @ W[m][koff..koff+K].T
// One row per thread; W tile staged in LDS, read via same-address broadcast.
template <int K>
__global__ __launch_bounds__(256) void gemm_kernel(
    const float* __restrict__ A, const float* __restrict__ W, int ldw, int koff,
    float* __restrict__ out, int n)
{
    __shared__ float wt[64 * K];
    const int t = threadIdx.x;
    const int m0 = blockIdx.y * 64;
    for (int e = t; e < 64 * K; e += 256) {
        int m = e / K, k = e - m * K;
        wt[e] = W[(size_t)(m0 + m) * ldw + koff + k];
    }
    __syncthreads();
    int row = blockIdx.x * 256 + t;
    if (row >= n) return;
    const float* a = A + (size_t)row * K;
    float acc[64];
    #pragma unroll
    for (int m = 0; m < 64; ++m) acc[m] = 0.f;
    for (int k = 0; k < K; k += 4) {
        float4 av = *(const float4*)(a + k);
        #pragma unroll
        for (int m = 0; m < 64; ++m) {
            float4 wv = *(const float4*)(&wt[m * K + k]);
            acc[m] = fmaf(av.x, wv.x, acc[m]);
            acc[m] = fmaf(av.y, wv.y, acc[m]);
            acc[m] = fmaf(av.z, wv.z, acc[m]);
            acc[m] = fmaf(av.w, wv.w, acc[m]);
        }
    }
    float* o = out + (size_t)row * 128 + m0;
    #pragma unroll
    for (int m = 0; m < 64; m += 4) {
        float4 v4 = make_float4(acc[m], acc[m + 1], acc[m + 2], acc[m + 3]);
        *(float4*)(o + m) = v4;
    }
}

// out[i][f] = opt_bn_relu( sum_{j in N(i)} tl[j][f] / max(deg,1) + bl[f] + tr[i][f] )
__global__ __launch_bounds__(128) void agg_kernel(
    const float* __restrict__ tl, const float* __restrict__ tr,
    const int* __restrict__ ptr, const int* __restrict__ edges,
    const float* __restrict__ bl,
    const float* __restrict__ bng, const float* __restrict__ bnb,
    const float* __restrict__ bnm, const float* __restrict__ bnv,
    int do_bn, float* __restrict__ out, int n)
{
    int i = blockIdx.x;
    int f = threadIdx.x;
    int p0 = ptr[i], p1 = ptr[i + 1];
    float sum = 0.f;
    for (int j = p0; j < p1; ++j) {
        int s = edges[j];
        sum += tl[(size_t)s * 128 + f];
    }
    float cnt = (float)(p1 - p0);
    float val = sum / fmaxf(cnt, 1.f) + bl[f] + tr[(size_t)i * 128 + f];
    if (do_bn) {
        float sc = bng[f] * rsqrtf(bnv[f] + 1e-5f);
        val = fmaxf(fmaf(val - bnm[f], sc, bnb[f]), 0.f);
    }
    out[(size_t)i * 128 + f] = val;
}

__global__ __launch_bounds__(256) void decode_kernel(
    const float* __restrict__ u, const float* __restrict__ v,
    const int* __restrict__ eli, const float* __restrict__ db1,
    const float* __restrict__ dw2, const float* __restrict__ db2,
    float* __restrict__ out, int L)
{
    __shared__ float sb[128], sw[128];
    if (threadIdx.x < 128) {
        sb[threadIdx.x] = db1[threadIdx.x];
        sw[threadIdx.x] = dw2[threadIdx.x];
    }
    __syncthreads();
    int p = blockIdx.x * 256 + threadIdx.x;
    if (p >= L) return;
    int s = eli[p], d = eli[L + p];
    const float* up = u + (size_t)s * 128;
    const float* vp = v + (size_t)d * 128;
    float acc = db2[0];
    #pragma unroll 8
    for (int o = 0; o < 128; o += 4) {
        float4 a  = *(const float4*)(up + o);
        float4 b  = *(const float4*)(vp + o);
        float4 bb = *(const float4*)(&sb[o]);
        float4 w  = *(const float4*)(&sw[o]);
        acc += fmaxf(a.x + b.x + bb.x, 0.f) * w.x;
        acc += fmaxf(a.y + b.y + bb.y, 0.f) * w.y;
        acc += fmaxf(a.z + b.z + bb.z, 0.f) * w.z;
        acc += fmaxf(a.w + b.w + bb.w, 0.f) * w.w;
    }
    out[p] = acc;
}

extern "C" void kernel_launch(void* const* d_in, const int* in_sizes, int n_in,
                              void* d_out, int out_size, void* d_ws, size_t ws_size,
                              hipStream_t stream)
{
    const float* x    = (const float*)d_in[0];
    const int*   ei   = (const int*)d_in[1];
    const int*   eli  = (const int*)d_in[2];
    const float* w1l  = (const float*)d_in[3];
    const float* b1l  = (const float*)d_in[4];
    const float* w1r  = (const float*)d_in[5];
    const float* w2l  = (const float*)d_in[6];
    const float* b2l  = (const float*)d_in[7];
    const float* w2r  = (const float*)d_in[8];
    const float* w3l  = (const float*)d_in[9];
    const float* b3l  = (const float*)d_in[10];
    const float* w3r  = (const float*)d_in[11];
    const float* bn1g = (const float*)d_in[12];
    const float* bn1b = (const float*)d_in[13];
    const float* bn1m = (const float*)d_in[14];
    const float* bn1v = (const float*)d_in[15];
    const float* bn2g = (const float*)d_in[16];
    const float* bn2b = (const float*)d_in[17];
    const float* bn2m = (const float*)d_in[18];
    const float* bn2v = (const float*)d_in[19];
    const float* dw1  = (const float*)d_in[20];
    const float* db1  = (const float*)d_in[21];
    const float* dw2  = (const float*)d_in[22];
    const float* db2  = (const float*)d_in[23];
    float* out = (float*)d_out;

    const int N = in_sizes[0] / 256;
    const int E = in_sizes[1] / 2;
    const int L = in_sizes[2] / 2;
    const int* src = ei;
    const int* dst = ei + E;

    char* ws = (char*)d_ws;
    int* ptr    = (int*)ws; ws += (size_t)(N + 1) * 4;
    int* cursor = (int*)ws; ws += (size_t)N * 4;
    int* edges  = (int*)ws; ws += (size_t)E * 4;
    float* tl   = (float*)ws; ws += (size_t)N * 128 * 4;
    float* tr   = (float*)ws; ws += (size_t)N * 128 * 4;
    float* h    = (float*)ws; ws += (size_t)N * 128 * 4;

    // ---- build CSR (dst -> list of src) ----
    hipMemsetAsync(cursor, 0, (size_t)N * 4, stream);
    count_kernel<<<(E + 255) / 256, 256, 0, stream>>>(dst, cursor, E);
    scan_kernel<<<1, 1024, 0, stream>>>(cursor, ptr, N);
    hipMemsetAsync(cursor, 0, (size_t)N * 4, stream);
    scatter_kernel<<<(E + 255) / 256, 256, 0, stream>>>(src, dst, ptr, cursor, edges, E);

    dim3 g((N + 255) / 256, 2);

    // ---- layer 1 (K=256) ----
    gemm_kernel<256><<<g, 256, 0, stream>>>(x, w1l, 256, 0, tl, N);
    gemm_kernel<256><<<g, 256, 0, stream>>>(x, w1r, 256, 0, tr, N);
    agg_kernel<<<N, 128, 0, stream>>>(tl, tr, ptr, edges, b1l,
                                      bn1g, bn1b, bn1m, bn1v, 1, h, N);

    // ---- layer 2 (K=128) ----
    gemm_kernel<128><<<g, 256, 0, stream>>>(h, w2l, 128, 0, tl, N);
    gemm_kernel<128><<<g, 256, 0, stream>>>(h, w2r, 128, 0, tr, N);
    agg_kernel<<<N, 128, 0, stream>>>(tl, tr, ptr, edges, b2l,
                                      bn2g, bn2b, bn2m, bn2v, 1, h, N);

    // ---- layer 3 (K=128, no BN/ReLU) ----
    gemm_kernel<128><<<g, 256, 0, stream>>>(h, w3l, 128, 0, tl, N);
    gemm_kernel<128><<<g, 256, 0, stream>>>(h, w3r, 128, 0, tr, N);
    agg_kernel<<<N, 128, 0, stream>>>(tl, tr, ptr, edges, b3l,
                                      bn1g, bn1b, bn1m, bn1v, 0, h, N);

    // ---- decoder per-node transforms: u = z@dw1[:, :128].T, v = z@dw1[:,128:].T ----
    gemm_kernel<128><<<g, 256, 0, stream>>>(h, dw1, 256, 0,   tl, N);
    gemm_kernel<128><<<g, 256, 0, stream>>>(h, dw1, 256, 128, tr, N);

    decode_kernel<<<(L + 255) / 256, 256, 0, stream>>>(tl, tr, eli, db1, dw2, db2, out, L);
}

// Round 2
// 536.213 us; speedup vs baseline: 2.2532x; 2.2532x over previous
//
#include <hip/hip_runtime.h>

// ---------------------------------------------------------------------------
// GraphSAGE (3x SAGEConv mean-agg + BN/ReLU) + link decoder.
// R2 changes vs R1:
//  - All GEMMs on MFMA (bf16 hi/lo split, K'=3K: Ah@Wh + Al@Wh + Ah@Wlo,
//    rel err ~2^-17 so f32-grade accuracy). Fused Wl|Wr -> one N_out=256 GEMM
//    per layer. 128x128 tile, 4 waves, 16x16x32 MFMA, LDS stride 72 (padded).
//  - agg emits bf16 hi/lo (next GEMM's input) directly; float4 per thread.
//  - CSR scan parallelized (tile scan + offset add) instead of 1-block serial.
// ---------------------------------------------------------------------------

typedef unsigned int uint;
using s16x8 = __attribute__((ext_vector_type(8))) short;
using f32x4 = __attribute__((ext_vector_type(4))) float;

__device__ inline void bsplit(float v, ushort& hi, ushort& lo) {
    // round-to-nearest-even bf16 split: v ~= hi + lo to ~2^-17 rel
    uint u = __float_as_uint(v);
    uint hb = (u + 0x7FFFu + ((u >> 16) & 1u)) >> 16;
    hi = (ushort)hb;
    float r = v - __uint_as_float(hb << 16);
    uint u2 = __float_as_uint(r);
    lo = (ushort)((u2 + 0x7FFFu + ((u2 >> 16) & 1u)) >> 16);
}

// ---------------- CSR build ----------------
__global__ void count_kernel(const int* __restrict__ dst, int* __restrict__ cnt, int E) {
    int i = blockIdx.x * blockDim.x + threadIdx.x;
    if (i < E) atomicAdd(&cnt[dst[i]], 1);
}

// per-tile exclusive scan (tile = 1024), writes tile sums
__global__ void scanA_kernel(const int* __restrict__ cnt, int* __restrict__ ptr,
                             int* __restrict__ tilesum, int n) {
    __shared__ int sd[1024];
    int t = threadIdx.x;
    int i = blockIdx.x * 1024 + t;
    int v = (i < n) ? cnt[i] : 0;
    sd[t] = v;
    __syncthreads();
    #pragma unroll
    for (int off = 1; off < 1024; off <<= 1) {
        int add = (t >= off) ? sd[t - off] : 0;
        __syncthreads();
        sd[t] += add;
        __syncthreads();
    }
    if (i < n) ptr[i] = sd[t] - v;              // local exclusive
    if (t == 1023) tilesum[blockIdx.x] = sd[t]; // tile total
}

__global__ void scanB_kernel(int* __restrict__ tilesum, int* __restrict__ ptr,
                             int ntiles, int n) {
    if (threadIdx.x == 0 && blockIdx.x == 0) {
        int running = 0;
        for (int b = 0; b < ntiles; ++b) {
            int t = tilesum[b];
            tilesum[b] = running;
            running += t;
        }
        ptr[n] = running;
    }
}

__global__ void scanC_kernel(int* __restrict__ ptr, const int* __restrict__ tilesum, int n) {
    int i = blockIdx.x * blockDim.x + threadIdx.x;
    if (i < n) ptr[i] += tilesum[i >> 10];
}

__global__ void scatter_kernel(const int* __restrict__ src, const int* __restrict__ dst,
                               const int* __restrict__ ptr, int* __restrict__ cursor,
                               int* __restrict__ edges, int E) {
    int i = blockIdx.x * blockDim.x + threadIdx.x;
    if (i < E) {
        int d = dst[i];
        int pos = ptr[d] + atomicAdd(&cursor[d], 1);
        edges[pos] = src[i];
    }
}

// ---------------- input / weight conversion to split-bf16 ----------------
// A3 row layout (K=256): [hi(0..255) | lo(0..255) | hi(0..255)]
__global__ __launch_bounds__(256) void convx_kernel(const float* __restrict__ x,
                                                    ushort* __restrict__ A3, int total) {
    int e = blockIdx.x * 256 + threadIdx.x;   // total = N*64 (float4 groups)
    if (e >= total) return;
    int row = e >> 6, k4 = (e & 63) << 2;
    float4 v = *(const float4*)(x + (size_t)row * 256 + k4);
    ushort4 hi, lo;
    bsplit(v.x, hi.x, lo.x); bsplit(v.y, hi.y, lo.y);
    bsplit(v.z, hi.z, lo.z); bsplit(v.w, hi.w, lo.w);
    ushort* d = A3 + (size_t)row * 768 + k4;
    *(ushort4*)(d)       = hi;
    *(ushort4*)(d + 256) = lo;
    *(ushort4*)(d + 512) = hi;
}

// WS[n][k'] n-major, k' = [Wh | Wh | Wlo]; n<128 from wa, n>=128 from wb
__global__ void wprep_kernel(const float* __restrict__ wa, const float* __restrict__ wb,
                             int K, int lda, int aoff, int boff, ushort* __restrict__ WS) {
    int n = blockIdx.x;
    int k = threadIdx.x;
    if (k >= K) return;
    const float* srcr = (n < 128) ? (wa + (size_t)n * lda + aoff)
                                  : (wb + (size_t)(n - 128) * lda + boff);
    ushort hi, lo;
    bsplit(srcr[k], hi, lo);
    ushort* d = WS + (size_t)n * 3 * K;
    d[k] = hi; d[K + k] = hi; d[2 * K + k] = lo;
}

// ---------------- MFMA GEMM: C[M][256] = A[M][KP]bf16 @ WS[256][KP]bf16^T ----
template <int KP>
__global__ __launch_bounds__(256) void mm_kernel(const ushort* __restrict__ A,
                                                 const ushort* __restrict__ WS,
                                                 float* __restrict__ C, int M) {
    constexpr int LDT = 72;                       // +8 bf16 pad: breaks 128B stride
    __shared__ ushort At[128 * LDT];
    __shared__ ushort Wt[128 * LDT];
    const int t = threadIdx.x;
    const int lane = t & 63;
    const int wave = t >> 6;
    const int wm = wave >> 1, wn = wave & 1;      // 2x2 waves, 64x64 each
    const int row0 = blockIdx.x * 128;
    const int n0 = blockIdx.y * 128;
    const int sr = t >> 1;                        // staged row per thread
    const int sh = (t & 1) * 32;                  // 32 bf16 = 64B half-row
    const int l15 = lane & 15;
    const int l4 = lane >> 4;

    f32x4 acc[4][4] = {};

    for (int kb = 0; kb < KP; kb += 64) {
        // ---- stage 128x64 A tile and 128x64 W tile (reg-staged, padded LDS)
        {
            ushort* la = &At[sr * LDT + sh];
            if (row0 + sr < M) {
                const ushort* ga = A + (size_t)(row0 + sr) * KP + kb + sh;
                #pragma unroll
                for (int c = 0; c < 32; c += 8)
                    *(s16x8*)(la + c) = *(const s16x8*)(ga + c);
            } else {
                s16x8 z = {0, 0, 0, 0, 0, 0, 0, 0};
                #pragma unroll
                for (int c = 0; c < 32; c += 8) *(s16x8*)(la + c) = z;
            }
            const ushort* gw = WS + (size_t)(n0 + sr) * KP + kb + sh;
            ushort* lw = &Wt[sr * LDT + sh];
            #pragma unroll
            for (int c = 0; c < 32; c += 8)
                *(s16x8*)(lw + c) = *(const s16x8*)(gw + c);
        }
        __syncthreads();
        #pragma unroll
        for (int kk = 0; kk < 64; kk += 32) {
            s16x8 af[4], bf[4];
            #pragma unroll
            for (int mi = 0; mi < 4; ++mi)
                af[mi] = *(const s16x8*)&At[(wm * 64 + mi * 16 + l15) * LDT + kk + l4 * 8];
            #pragma unroll
            for (int ni = 0; ni < 4; ++ni)
                bf[ni] = *(const s16x8*)&Wt[(wn * 64 + ni * 16 + l15) * LDT + kk + l4 * 8];
            #pragma unroll
            for (int mi = 0; mi < 4; ++mi)
                #pragma unroll
                for (int ni = 0; ni < 4; ++ni)
                    acc[mi][ni] = __builtin_amdgcn_mfma_f32_16x16x32_bf16(
                        af[mi], bf[ni], acc[mi][ni], 0, 0, 0);
        }
        __syncthreads();
    }
    // ---- epilogue: C/D layout col=lane&15, row=(lane>>4)*4+j
    #pragma unroll
    for (int mi = 0; mi < 4; ++mi) {
        int rbase = row0 + wm * 64 + mi * 16 + l4 * 4;
        #pragma unroll
        for (int ni = 0; ni < 4; ++ni) {
            int col = n0 + wn * 64 + ni * 16 + l15;
            #pragma unroll
            for (int j = 0; j < 4; ++j) {
                int r = rbase + j;
                if (r < M) C[(size_t)r * 256 + col] = acc[mi][ni][j];
            }
        }
    }
}

// ---------------- aggregation: mean-gather + bias + root + optional BN/ReLU,
// emits next GEMM's split-bf16 input h3[n][384] = [hi|lo|hi] ----------------
__global__ __launch_bounds__(256) void agg_kernel(
    const float* __restrict__ tlr, const int* __restrict__ ptr,
    const int* __restrict__ edges, const float* __restrict__ bl,
    const float* __restrict__ bng, const float* __restrict__ bnb,
    const float* __restrict__ bnm, const float* __restrict__ bnv,
    int do_bn, ushort* __restrict__ h3, int n) {
    int node = blockIdx.x * 8 + (threadIdx.x >> 5);
    if (node >= n) return;
    int q4 = (threadIdx.x & 31) << 2;             // 4 feats per thread
    int p0 = ptr[node], p1 = ptr[node + 1];
    float4 s = make_float4(0.f, 0.f, 0.f, 0.f);
    for (int e = p0; e < p1; ++e) {
        int src = edges[e];
        float4 v = *(const float4*)(tlr + (size_t)src * 256 + q4);
        s.x += v.x; s.y += v.y; s.z += v.z; s.w += v.w;
    }
    float inv = 1.f / fmaxf((float)(p1 - p0), 1.f);
    float4 r = *(const float4*)(tlr + (size_t)node * 256 + 128 + q4);
    float4 b = *(const float4*)(bl + q4);
    float4 val;
    val.x = fmaf(s.x, inv, b.x) + r.x;
    val.y = fmaf(s.y, inv, b.y) + r.y;
    val.z = fmaf(s.z, inv, b.z) + r.z;
    val.w = fmaf(s.w, inv, b.w) + r.w;
    if (do_bn) {
        float4 g = *(const float4*)(bng + q4);
        float4 be = *(const float4*)(bnb + q4);
        float4 m = *(const float4*)(bnm + q4);
        float4 vv = *(const float4*)(bnv + q4);
        val.x = fmaxf(fmaf(val.x - m.x, g.x * rsqrtf(vv.x + 1e-5f), be.x), 0.f);
        val.y = fmaxf(fmaf(val.y - m.y, g.y * rsqrtf(vv.y + 1e-5f), be.y), 0.f);
        val.z = fmaxf(fmaf(val.z - m.z, g.z * rsqrtf(vv.z + 1e-5f), be.z), 0.f);
        val.w = fmaxf(fmaf(val.w - m.w, g.w * rsqrtf(vv.w + 1e-5f), be.w), 0.f);
    }
    ushort4 hi, lo;
    bsplit(val.x, hi.x, lo.x); bsplit(val.y, hi.y, lo.y);
    bsplit(val.z, hi.z, lo.z); bsplit(val.w, hi.w, lo.w);
    ushort* d = h3 + (size_t)node * 384 + q4;
    *(ushort4*)(d)       = hi;
    *(ushort4*)(d + 128) = lo;
    *(ushort4*)(d + 256) = hi;
}

// ---------------- decoder: relu(u[s] + v[d] + b) . w2 + b2 ----------------
__global__ __launch_bounds__(256) void decode_kernel(
    const float* __restrict__ tlr, const int* __restrict__ eli,
    const float* __restrict__ db1, const float* __restrict__ dw2,
    const float* __restrict__ db2, float* __restrict__ out, int L) {
    __shared__ float sb[128], sw[128];
    if (threadIdx.x < 128) {
        sb[threadIdx.x] = db1[threadIdx.x];
        sw[threadIdx.x] = dw2[threadIdx.x];
    }
    __syncthreads();
    int p = blockIdx.x * 256 + threadIdx.x;
    if (p >= L) return;
    int s = eli[p], d = eli[L + p];
    const float* up = tlr + (size_t)s * 256;        // u = cols 0..127
    const float* vp = tlr + (size_t)d * 256 + 128;  // v = cols 128..255
    float acc = db2[0];
    #pragma unroll 8
    for (int o = 0; o < 128; o += 4) {
        float4 a = *(const float4*)(up + o);
        float4 b = *(const float4*)(vp + o);
        float4 bb = *(const float4*)(&sb[o]);
        float4 w = *(const float4*)(&sw[o]);
        acc += fmaxf(a.x + b.x + bb.x, 0.f) * w.x;
        acc += fmaxf(a.y + b.y + bb.y, 0.f) * w.y;
        acc += fmaxf(a.z + b.z + bb.z, 0.f) * w.z;
        acc += fmaxf(a.w + b.w + bb.w, 0.f) * w.w;
    }
    out[p] = acc;
}

extern "C" void kernel_launch(void* const* d_in, const int* in_sizes, int n_in,
                              void* d_out, int out_size, void* d_ws, size_t ws_size,
                              hipStream_t stream) {
    const float* x    = (const float*)d_in[0];
    const int*   ei   = (const int*)d_in[1];
    const int*   eli  = (const int*)d_in[2];
    const float* w1l  = (const float*)d_in[3];
    const float* b1l  = (const float*)d_in[4];
    const float* w1r  = (const float*)d_in[5];
    const float* w2l  = (const float*)d_in[6];
    const float* b2l  = (const float*)d_in[7];
    const float* w2r  = (const float*)d_in[8];
    const float* w3l  = (const float*)d_in[9];
    const float* b3l  = (const float*)d_in[10];
    const float* w3r  = (const float*)d_in[11];
    const float* bn1g = (const float*)d_in[12];
    const float* bn1b = (const float*)d_in[13];
    const float* bn1m = (const float*)d_in[14];
    const float* bn1v = (const float*)d_in[15];
    const float* bn2g = (const float*)d_in[16];
    const float* bn2b = (const float*)d_in[17];
    const float* bn2m = (const float*)d_in[18];
    const float* bn2v = (const float*)d_in[19];
    const float* dw1  = (const float*)d_in[20];
    const float* db1  = (const float*)d_in[21];
    const float* dw2  = (const float*)d_in[22];
    const float* db2  = (const float*)d_in[23];
    float* out = (float*)d_out;

    const int N = in_sizes[0] / 256;
    const int E = in_sizes[1] / 2;
    const int L = in_sizes[2] / 2;
    const int* src = ei;
    const int* dst = ei + E;
    const int ntiles = (N + 1023) >> 10;

    // ---- workspace carve (256B aligned) ----
    char* wsb = (char*)d_ws;
    size_t off = 0;
    auto carve = [&](size_t bytes) -> void* {
        void* p = wsb + off;
        off += (bytes + 255) & ~(size_t)255;
        return p;
    };
    int* ptr        = (int*)carve((size_t)(N + 1) * 4);
    int* cursor     = (int*)carve((size_t)N * 4);
    int* tilesum    = (int*)carve((size_t)ntiles * 4);
    int* edges      = (int*)carve((size_t)E * 4);
    ushort* WS1     = (ushort*)carve((size_t)256 * 768 * 2);
    ushort* WS2     = (ushort*)carve((size_t)256 * 384 * 2);
    ushort* WS3     = (ushort*)carve((size_t)256 * 384 * 2);
    ushort* WS4     = (ushort*)carve((size_t)256 * 384 * 2);
    float* tlr      = (float*)carve((size_t)N * 256 * 4);       // gemm out (tl|tr)
    ushort* A3      = (ushort*)carve((size_t)N * 768 * 2);      // layer-1 split input
    ushort* h3      = A3;                                       // reuse: [N][384] after mm1

    // ---- CSR build ----
    hipMemsetAsync(cursor, 0, (size_t)N * 4, stream);
    count_kernel<<<(E + 255) / 256, 256, 0, stream>>>(dst, cursor, E);
    scanA_kernel<<<ntiles, 1024, 0, stream>>>(cursor, ptr, tilesum, N);
    scanB_kernel<<<1, 64, 0, stream>>>(tilesum, ptr, ntiles, N);
    scanC_kernel<<<(N + 255) / 256, 256, 0, stream>>>(ptr, tilesum, N);
    hipMemsetAsync(cursor, 0, (size_t)N * 4, stream);
    scatter_kernel<<<(E + 255) / 256, 256, 0, stream>>>(src, dst, ptr, cursor, edges, E);

    // ---- conversions ----
    convx_kernel<<<(N * 64 + 255) / 256, 256, 0, stream>>>(x, A3, N * 64);
    wprep_kernel<<<256, 256, 0, stream>>>(w1l, w1r, 256, 256, 0, 0, WS1);
    wprep_kernel<<<256, 256, 0, stream>>>(w2l, w2r, 128, 128, 0, 0, WS2);
    wprep_kernel<<<256, 256, 0, stream>>>(w3l, w3r, 128, 128, 0, 0, WS3);
    wprep_kernel<<<256, 256, 0, stream>>>(dw1, dw1, 128, 256, 0, 128, WS4);

    dim3 mg((N + 127) / 128, 2);

    // ---- layer 1 ----
    mm_kernel<768><<<mg, 256, 0, stream>>>(A3, WS1, tlr, N);
    agg_kernel<<<(N + 7) / 8, 256, 0, stream>>>(tlr, ptr, edges, b1l,
                                                bn1g, bn1b, bn1m, bn1v, 1, h3, N);
    // ---- layer 2 ----
    mm_kernel<384><<<mg, 256, 0, stream>>>(h3, WS2, tlr, N);
    agg_kernel<<<(N + 7) / 8, 256, 0, stream>>>(tlr, ptr, edges, b2l,
                                                bn2g, bn2b, bn2m, bn2v, 1, h3, N);
    // ---- layer 3 (no BN) ----
    mm_kernel<384><<<mg, 256, 0, stream>>>(h3, WS3, tlr, N);
    agg_kernel<<<(N + 7) / 8, 256, 0, stream>>>(tlr, ptr, edges, b3l,
                                                bn1g, bn1b, bn1m, bn1v, 0, h3, N);
    // ---- decoder transforms u|v, then pair decode ----
    mm_kernel<384><<<mg, 256, 0, stream>>>(h3, WS4, tlr, N);
    decode_kernel<<<(L + 255) / 256, 256, 0, stream>>>(tlr, eli, db1, dw2, db2, out, L);
}

// Round 3
// 508.052 us; speedup vs baseline: 2.3781x; 1.0554x over previous
//
#include <hip/hip_runtime.h>

// ---------------------------------------------------------------------------
// GraphSAGE (3x SAGEConv mean-agg + BN/ReLU) + link decoder.
// R3 changes vs R2:
//  - GEMM writes split compact outputs tl_c[N][128], tr_c[N][128] (gather
//    working set 51.2MB -> 25.6MB, better L2/L3 residency)
//  - agg: 4-way edge unroll, 4 independent accumulators (gather MLP)
//  - decode reads compact buffers; 4 wprep launches merged into 1
// ---------------------------------------------------------------------------

typedef unsigned int uint;
using s16x8 = __attribute__((ext_vector_type(8))) short;
using f32x4 = __attribute__((ext_vector_type(4))) float;

__device__ inline void bsplit(float v, ushort& hi, ushort& lo) {
    // round-to-nearest-even bf16 split: v ~= hi + lo to ~2^-17 rel
    uint u = __float_as_uint(v);
    uint hb = (u + 0x7FFFu + ((u >> 16) & 1u)) >> 16;
    hi = (ushort)hb;
    float r = v - __uint_as_float(hb << 16);
    uint u2 = __float_as_uint(r);
    lo = (ushort)((u2 + 0x7FFFu + ((u2 >> 16) & 1u)) >> 16);
}

// ---------------- CSR build ----------------
__global__ void count_kernel(const int* __restrict__ dst, int* __restrict__ cnt, int E) {
    int i = blockIdx.x * blockDim.x + threadIdx.x;
    if (i < E) atomicAdd(&cnt[dst[i]], 1);
}

__global__ void scanA_kernel(const int* __restrict__ cnt, int* __restrict__ ptr,
                             int* __restrict__ tilesum, int n) {
    __shared__ int sd[1024];
    int t = threadIdx.x;
    int i = blockIdx.x * 1024 + t;
    int v = (i < n) ? cnt[i] : 0;
    sd[t] = v;
    __syncthreads();
    #pragma unroll
    for (int off = 1; off < 1024; off <<= 1) {
        int add = (t >= off) ? sd[t - off] : 0;
        __syncthreads();
        sd[t] += add;
        __syncthreads();
    }
    if (i < n) ptr[i] = sd[t] - v;              // local exclusive
    if (t == 1023) tilesum[blockIdx.x] = sd[t]; // tile total
}

__global__ void scanB_kernel(int* __restrict__ tilesum, int* __restrict__ ptr,
                             int ntiles, int n) {
    if (threadIdx.x == 0 && blockIdx.x == 0) {
        int running = 0;
        for (int b = 0; b < ntiles; ++b) {
            int t = tilesum[b];
            tilesum[b] = running;
            running += t;
        }
        ptr[n] = running;
    }
}

__global__ void scanC_kernel(int* __restrict__ ptr, const int* __restrict__ tilesum, int n) {
    int i = blockIdx.x * blockDim.x + threadIdx.x;
    if (i < n) ptr[i] += tilesum[i >> 10];
}

__global__ void scatter_kernel(const int* __restrict__ src, const int* __restrict__ dst,
                               const int* __restrict__ ptr, int* __restrict__ cursor,
                               int* __restrict__ edges, int E) {
    int i = blockIdx.x * blockDim.x + threadIdx.x;
    if (i < E) {
        int d = dst[i];
        int pos = ptr[d] + atomicAdd(&cursor[d], 1);
        edges[pos] = src[i];
    }
}

// ---------------- input / weight conversion to split-bf16 ----------------
// A3 row layout (K=256): [hi(0..255) | lo(0..255) | hi(0..255)]
__global__ __launch_bounds__(256) void convx_kernel(const float* __restrict__ x,
                                                    ushort* __restrict__ A3, int total) {
    int e = blockIdx.x * 256 + threadIdx.x;   // total = N*64 (float4 groups)
    if (e >= total) return;
    int row = e >> 6, k4 = (e & 63) << 2;
    float4 v = *(const float4*)(x + (size_t)row * 256 + k4);
    ushort4 hi, lo;
    bsplit(v.x, hi.x, lo.x); bsplit(v.y, hi.y, lo.y);
    bsplit(v.z, hi.z, lo.z); bsplit(v.w, hi.w, lo.w);
    ushort* d = A3 + (size_t)row * 768 + k4;
    *(ushort4*)(d)       = hi;
    *(ushort4*)(d + 256) = lo;
    *(ushort4*)(d + 512) = hi;
}

// All weight preps in one launch. WS[n][k'] n-major, k' = [Wh | Wh | Wlo]
__global__ void wprep_all_kernel(
    const float* __restrict__ w1l, const float* __restrict__ w1r,
    const float* __restrict__ w2l, const float* __restrict__ w2r,
    const float* __restrict__ w3l, const float* __restrict__ w3r,
    const float* __restrict__ dw1,
    ushort* __restrict__ WS1, ushort* __restrict__ WS2,
    ushort* __restrict__ WS3, ushort* __restrict__ WS4)
{
    int which = blockIdx.y;
    int n = blockIdx.x;
    int k = threadIdx.x;
    const float *wa, *wb;
    int K, lda, aoff, boff;
    ushort* WS;
    switch (which) {
        case 0:  wa = w1l; wb = w1r; K = 256; lda = 256; aoff = 0; boff = 0;   WS = WS1; break;
        case 1:  wa = w2l; wb = w2r; K = 128; lda = 128; aoff = 0; boff = 0;   WS = WS2; break;
        case 2:  wa = w3l; wb = w3r; K = 128; lda = 128; aoff = 0; boff = 0;   WS = WS3; break;
        default: wa = dw1; wb = dw1; K = 128; lda = 256; aoff = 0; boff = 128; WS = WS4; break;
    }
    if (k >= K) return;
    const float* srcr = (n < 128) ? (wa + (size_t)n * lda + aoff)
                                  : (wb + (size_t)(n - 128) * lda + boff);
    ushort hi, lo;
    bsplit(srcr[k], hi, lo);
    ushort* d = WS + (size_t)n * 3 * K;
    d[k] = hi; d[K + k] = hi; d[2 * K + k] = lo;
}

// ---------------- MFMA GEMM ----------------
// C = A[M][KP]bf16 @ WS[256][KP]bf16^T ; cols 0..127 -> Cl[M][128],
// cols 128..255 -> Cr[M][128] (blockIdx.y selects half)
template <int KP>
__global__ __launch_bounds__(256) void mm_kernel(const ushort* __restrict__ A,
                                                 const ushort* __restrict__ WS,
                                                 float* __restrict__ Cl,
                                                 float* __restrict__ Cr, int M) {
    constexpr int LDT = 72;                       // +8 bf16 pad: breaks 128B stride
    __shared__ ushort At[128 * LDT];
    __shared__ ushort Wt[128 * LDT];
    const int t = threadIdx.x;
    const int lane = t & 63;
    const int wave = t >> 6;
    const int wm = wave >> 1, wn = wave & 1;      // 2x2 waves, 64x64 each
    const int row0 = blockIdx.x * 128;
    const int n0 = blockIdx.y * 128;
    const int sr = t >> 1;
    const int sh = (t & 1) * 32;
    const int l15 = lane & 15;
    const int l4 = lane >> 4;

    f32x4 acc[4][4] = {};

    for (int kb = 0; kb < KP; kb += 64) {
        {
            ushort* la = &At[sr * LDT + sh];
            if (row0 + sr < M) {
                const ushort* ga = A + (size_t)(row0 + sr) * KP + kb + sh;
                #pragma unroll
                for (int c = 0; c < 32; c += 8)
                    *(s16x8*)(la + c) = *(const s16x8*)(ga + c);
            } else {
                s16x8 z = {0, 0, 0, 0, 0, 0, 0, 0};
                #pragma unroll
                for (int c = 0; c < 32; c += 8) *(s16x8*)(la + c) = z;
            }
            const ushort* gw = WS + (size_t)(n0 + sr) * KP + kb + sh;
            ushort* lw = &Wt[sr * LDT + sh];
            #pragma unroll
            for (int c = 0; c < 32; c += 8)
                *(s16x8*)(lw + c) = *(const s16x8*)(gw + c);
        }
        __syncthreads();
        #pragma unroll
        for (int kk = 0; kk < 64; kk += 32) {
            s16x8 af[4], bf[4];
            #pragma unroll
            for (int mi = 0; mi < 4; ++mi)
                af[mi] = *(const s16x8*)&At[(wm * 64 + mi * 16 + l15) * LDT + kk + l4 * 8];
            #pragma unroll
            for (int ni = 0; ni < 4; ++ni)
                bf[ni] = *(const s16x8*)&Wt[(wn * 64 + ni * 16 + l15) * LDT + kk + l4 * 8];
            #pragma unroll
            for (int mi = 0; mi < 4; ++mi)
                #pragma unroll
                for (int ni = 0; ni < 4; ++ni)
                    acc[mi][ni] = __builtin_amdgcn_mfma_f32_16x16x32_bf16(
                        af[mi], bf[ni], acc[mi][ni], 0, 0, 0);
        }
        __syncthreads();
    }
    float* base = (blockIdx.y == 0) ? Cl : Cr;
    #pragma unroll
    for (int mi = 0; mi < 4; ++mi) {
        int rbase = row0 + wm * 64 + mi * 16 + l4 * 4;
        #pragma unroll
        for (int ni = 0; ni < 4; ++ni) {
            int col = wn * 64 + ni * 16 + l15;            // 0..127 within half
            #pragma unroll
            for (int j = 0; j < 4; ++j) {
                int r = rbase + j;
                if (r < M) base[(size_t)r * 128 + col] = acc[mi][ni][j];
            }
        }
    }
}

// ---------------- aggregation ----------------
// out = opt_bn_relu( mean_{src in N(i)} tl[src] + bl + tr[i] ), emits split-bf16
__global__ __launch_bounds__(256) void agg_kernel(
    const float* __restrict__ tl, const float* __restrict__ tr,
    const int* __restrict__ ptr, const int* __restrict__ edges,
    const float* __restrict__ bl,
    const float* __restrict__ bng, const float* __restrict__ bnb,
    const float* __restrict__ bnm, const float* __restrict__ bnv,
    int do_bn, ushort* __restrict__ h3, int n) {
    int node = blockIdx.x * 8 + (threadIdx.x >> 5);
    if (node >= n) return;
    int q4 = (threadIdx.x & 31) << 2;             // 4 feats per thread
    int p0 = ptr[node], p1 = ptr[node + 1];
    float4 s0 = make_float4(0.f, 0.f, 0.f, 0.f), s1 = s0, s2 = s0, s3 = s0;
    int e = p0;
    for (; e + 4 <= p1; e += 4) {
        int i0 = edges[e], i1 = edges[e + 1], i2 = edges[e + 2], i3 = edges[e + 3];
        float4 v0 = *(const float4*)(tl + (size_t)i0 * 128 + q4);
        float4 v1 = *(const float4*)(tl + (size_t)i1 * 128 + q4);
        float4 v2 = *(const float4*)(tl + (size_t)i2 * 128 + q4);
        float4 v3 = *(const float4*)(tl + (size_t)i3 * 128 + q4);
        s0.x += v0.x; s0.y += v0.y; s0.z += v0.z; s0.w += v0.w;
        s1.x += v1.x; s1.y += v1.y; s1.z += v1.z; s1.w += v1.w;
        s2.x += v2.x; s2.y += v2.y; s2.z += v2.z; s2.w += v2.w;
        s3.x += v3.x; s3.y += v3.y; s3.z += v3.z; s3.w += v3.w;
    }
    for (; e < p1; ++e) {
        int i0 = edges[e];
        float4 v0 = *(const float4*)(tl + (size_t)i0 * 128 + q4);
        s0.x += v0.x; s0.y += v0.y; s0.z += v0.z; s0.w += v0.w;
    }
    float4 s;
    s.x = (s0.x + s1.x) + (s2.x + s3.x);
    s.y = (s0.y + s1.y) + (s2.y + s3.y);
    s.z = (s0.z + s1.z) + (s2.z + s3.z);
    s.w = (s0.w + s1.w) + (s2.w + s3.w);
    float inv = 1.f / fmaxf((float)(p1 - p0), 1.f);
    float4 r = *(const float4*)(tr + (size_t)node * 128 + q4);
    float4 b = *(const float4*)(bl + q4);
    float4 val;
    val.x = fmaf(s.x, inv, b.x) + r.x;
    val.y = fmaf(s.y, inv, b.y) + r.y;
    val.z = fmaf(s.z, inv, b.z) + r.z;
    val.w = fmaf(s.w, inv, b.w) + r.w;
    if (do_bn) {
        float4 g = *(const float4*)(bng + q4);
        float4 be = *(const float4*)(bnb + q4);
        float4 m = *(const float4*)(bnm + q4);
        float4 vv = *(const float4*)(bnv + q4);
        val.x = fmaxf(fmaf(val.x - m.x, g.x * rsqrtf(vv.x + 1e-5f), be.x), 0.f);
        val.y = fmaxf(fmaf(val.y - m.y, g.y * rsqrtf(vv.y + 1e-5f), be.y), 0.f);
        val.z = fmaxf(fmaf(val.z - m.z, g.z * rsqrtf(vv.z + 1e-5f), be.z), 0.f);
        val.w = fmaxf(fmaf(val.w - m.w, g.w * rsqrtf(vv.w + 1e-5f), be.w), 0.f);
    }
    ushort4 hi, lo;
    bsplit(val.x, hi.x, lo.x); bsplit(val.y, hi.y, lo.y);
    bsplit(val.z, hi.z, lo.z); bsplit(val.w, hi.w, lo.w);
    ushort* d = h3 + (size_t)node * 384 + q4;
    *(ushort4*)(d)       = hi;
    *(ushort4*)(d + 128) = lo;
    *(ushort4*)(d + 256) = hi;
}

// ---------------- decoder: relu(u[s] + v[d] + b) . w2 + b2 ----------------
__global__ __launch_bounds__(256) void decode_kernel(
    const float* __restrict__ u, const float* __restrict__ v,
    const int* __restrict__ eli, const float* __restrict__ db1,
    const float* __restrict__ dw2, const float* __restrict__ db2,
    float* __restrict__ out, int L) {
    __shared__ float sb[128], sw[128];
    if (threadIdx.x < 128) {
        sb[threadIdx.x] = db1[threadIdx.x];
        sw[threadIdx.x] = dw2[threadIdx.x];
    }
    __syncthreads();
    int p = blockIdx.x * 256 + threadIdx.x;
    if (p >= L) return;
    int s = eli[p], d = eli[L + p];
    const float* up = u + (size_t)s * 128;
    const float* vp = v + (size_t)d * 128;
    float acc = db2[0];
    #pragma unroll 8
    for (int o = 0; o < 128; o += 4) {
        float4 a = *(const float4*)(up + o);
        float4 b = *(const float4*)(vp + o);
        float4 bb = *(const float4*)(&sb[o]);
        float4 w = *(const float4*)(&sw[o]);
        acc += fmaxf(a.x + b.x + bb.x, 0.f) * w.x;
        acc += fmaxf(a.y + b.y + bb.y, 0.f) * w.y;
        acc += fmaxf(a.z + b.z + bb.z, 0.f) * w.z;
        acc += fmaxf(a.w + b.w + bb.w, 0.f) * w.w;
    }
    out[p] = acc;
}

extern "C" void kernel_launch(void* const* d_in, const int* in_sizes, int n_in,
                              void* d_out, int out_size, void* d_ws, size_t ws_size,
                              hipStream_t stream) {
    const float* x    = (const float*)d_in[0];
    const int*   ei   = (const int*)d_in[1];
    const int*   eli  = (const int*)d_in[2];
    const float* w1l  = (const float*)d_in[3];
    const float* b1l  = (const float*)d_in[4];
    const float* w1r  = (const float*)d_in[5];
    const float* w2l  = (const float*)d_in[6];
    const float* b2l  = (const float*)d_in[7];
    const float* w2r  = (const float*)d_in[8];
    const float* w3l  = (const float*)d_in[9];
    const float* b3l  = (const float*)d_in[10];
    const float* w3r  = (const float*)d_in[11];
    const float* bn1g = (const float*)d_in[12];
    const float* bn1b = (const float*)d_in[13];
    const float* bn1m = (const float*)d_in[14];
    const float* bn1v = (const float*)d_in[15];
    const float* bn2g = (const float*)d_in[16];
    const float* bn2b = (const float*)d_in[17];
    const float* bn2m = (const float*)d_in[18];
    const float* bn2v = (const float*)d_in[19];
    const float* dw1  = (const float*)d_in[20];
    const float* db1  = (const float*)d_in[21];
    const float* dw2  = (const float*)d_in[22];
    const float* db2  = (const float*)d_in[23];
    float* out = (float*)d_out;

    const int N = in_sizes[0] / 256;
    const int E = in_sizes[1] / 2;
    const int L = in_sizes[2] / 2;
    const int* src = ei;
    const int* dst = ei + E;
    const int ntiles = (N + 1023) >> 10;

    char* wsb = (char*)d_ws;
    size_t off = 0;
    auto carve = [&](size_t bytes) -> void* {
        void* p = wsb + off;
        off += (bytes + 255) & ~(size_t)255;
        return p;
    };
    int* ptr        = (int*)carve((size_t)(N + 1) * 4);
    int* cursor     = (int*)carve((size_t)N * 4);
    int* tilesum    = (int*)carve((size_t)ntiles * 4);
    int* edges      = (int*)carve((size_t)E * 4);
    ushort* WS1     = (ushort*)carve((size_t)256 * 768 * 2);
    ushort* WS2     = (ushort*)carve((size_t)256 * 384 * 2);
    ushort* WS3     = (ushort*)carve((size_t)256 * 384 * 2);
    ushort* WS4     = (ushort*)carve((size_t)256 * 384 * 2);
    float* tl_c     = (float*)carve((size_t)N * 128 * 4);   // neighbor-transform
    float* tr_c     = (float*)carve((size_t)N * 128 * 4);   // root-transform
    ushort* A3      = (ushort*)carve((size_t)N * 768 * 2);  // layer-1 split input
    ushort* h3      = A3;                                   // reuse after mm1

    // ---- CSR build ----
    hipMemsetAsync(cursor, 0, (size_t)N * 4, stream);
    count_kernel<<<(E + 255) / 256, 256, 0, stream>>>(dst, cursor, E);
    scanA_kernel<<<ntiles, 1024, 0, stream>>>(cursor, ptr, tilesum, N);
    scanB_kernel<<<1, 64, 0, stream>>>(tilesum, ptr, ntiles, N);
    scanC_kernel<<<(N + 255) / 256, 256, 0, stream>>>(ptr, tilesum, N);
    hipMemsetAsync(cursor, 0, (size_t)N * 4, stream);
    scatter_kernel<<<(E + 255) / 256, 256, 0, stream>>>(src, dst, ptr, cursor, edges, E);

    // ---- conversions ----
    convx_kernel<<<(N * 64 + 255) / 256, 256, 0, stream>>>(x, A3, N * 64);
    wprep_all_kernel<<<dim3(256, 4), 256, 0, stream>>>(w1l, w1r, w2l, w2r, w3l, w3r,
                                                       dw1, WS1, WS2, WS3, WS4);

    dim3 mg((N + 127) / 128, 2);

    // ---- layer 1 ----
    mm_kernel<768><<<mg, 256, 0, stream>>>(A3, WS1, tl_c, tr_c, N);
    agg_kernel<<<(N + 7) / 8, 256, 0, stream>>>(tl_c, tr_c, ptr, edges, b1l,
                                                bn1g, bn1b, bn1m, bn1v, 1, h3, N);
    // ---- layer 2 ----
    mm_kernel<384><<<mg, 256, 0, stream>>>(h3, WS2, tl_c, tr_c, N);
    agg_kernel<<<(N + 7) / 8, 256, 0, stream>>>(tl_c, tr_c, ptr, edges, b2l,
                                                bn2g, bn2b, bn2m, bn2v, 1, h3, N);
    // ---- layer 3 (no BN) ----
    mm_kernel<384><<<mg, 256, 0, stream>>>(h3, WS3, tl_c, tr_c, N);
    agg_kernel<<<(N + 7) / 8, 256, 0, stream>>>(tl_c, tr_c, ptr, edges, b3l,
                                                bn1g, bn1b, bn1m, bn1v, 0, h3, N);
    // ---- decoder transforms u|v, then pair decode ----
    mm_kernel<384><<<mg, 256, 0, stream>>>(h3, WS4, tl_c, tr_c, N);
    decode_kernel<<<(L + 255) / 256, 256, 0, stream>>>(tl_c, tr_c, eli, db1, dw2, db2, out, L);
}

// Round 5
// 457.583 us; speedup vs baseline: 2.6403x; 1.1103x over previous
//
#include <hip/hip_runtime.h>

// ---------------------------------------------------------------------------
// GraphSAGE (3x SAGEConv mean-agg + BN/ReLU) + link decoder.
// R5 = R4 with the K-step schedule bug fixed:
//   A = [hi|lo] (K/64*2 slices), W = [Wh|Wlo|Wh] (3K/64 slices)
//   as = (s < K/64) ? s : s - K/64   where K/64 == KP/128   (was KP/64: WRONG,
//   computed 2*Ah*Wh + Alo*Wlo instead of Ah*Wh + Ah*Wlo + Alo*Wh)
// ---------------------------------------------------------------------------

typedef unsigned int uint;
using s16x8 = __attribute__((ext_vector_type(8))) short;
using f32x4 = __attribute__((ext_vector_type(4))) float;

__device__ inline void bsplit(float v, ushort& hi, ushort& lo) {
    // round-to-nearest-even bf16 split: v ~= hi + lo to ~2^-17 rel
    uint u = __float_as_uint(v);
    uint hb = (u + 0x7FFFu + ((u >> 16) & 1u)) >> 16;
    hi = (ushort)hb;
    float r = v - __uint_as_float(hb << 16);
    uint u2 = __float_as_uint(r);
    lo = (ushort)((u2 + 0x7FFFu + ((u2 >> 16) & 1u)) >> 16);
}

// ---------------- CSR build ----------------
__global__ void count_kernel(const int* __restrict__ dst, int* __restrict__ cnt, int E) {
    int i = blockIdx.x * blockDim.x + threadIdx.x;
    if (i < E) atomicAdd(&cnt[dst[i]], 1);
}

__global__ void scanA_kernel(const int* __restrict__ cnt, int* __restrict__ ptr,
                             int* __restrict__ tilesum, int n) {
    __shared__ int sd[1024];
    int t = threadIdx.x;
    int i = blockIdx.x * 1024 + t;
    int v = (i < n) ? cnt[i] : 0;
    sd[t] = v;
    __syncthreads();
    #pragma unroll
    for (int off = 1; off < 1024; off <<= 1) {
        int add = (t >= off) ? sd[t - off] : 0;
        __syncthreads();
        sd[t] += add;
        __syncthreads();
    }
    if (i < n) ptr[i] = sd[t] - v;              // local exclusive
    if (t == 1023) tilesum[blockIdx.x] = sd[t]; // tile total
}

__global__ void scanB_kernel(int* __restrict__ tilesum, int* __restrict__ ptr,
                             int ntiles, int n) {
    if (threadIdx.x == 0 && blockIdx.x == 0) {
        int running = 0;
        for (int b = 0; b < ntiles; ++b) {
            int t = tilesum[b];
            tilesum[b] = running;
            running += t;
        }
        ptr[n] = running;
    }
}

__global__ void scanC_kernel(int* __restrict__ ptr, const int* __restrict__ tilesum, int n) {
    int i = blockIdx.x * blockDim.x + threadIdx.x;
    if (i < n) ptr[i] += tilesum[i >> 10];
}

__global__ void scatter_kernel(const int* __restrict__ src, const int* __restrict__ dst,
                               const int* __restrict__ ptr, int* __restrict__ cursor,
                               int* __restrict__ edges, int E) {
    int i = blockIdx.x * blockDim.x + threadIdx.x;
    if (i < E) {
        int d = dst[i];
        int pos = ptr[d] + atomicAdd(&cursor[d], 1);
        edges[pos] = src[i];
    }
}

// ---------------- conversions ----------------
// A row (K=256): [hi(0..255) | lo(0..255)]  (KP=512)
__global__ __launch_bounds__(256) void convx_kernel(const float* __restrict__ x,
                                                    ushort* __restrict__ A3, int total) {
    int e = blockIdx.x * 256 + threadIdx.x;   // total = N*64 (float4 groups)
    if (e >= total) return;
    int row = e >> 6, k4 = (e & 63) << 2;
    float4 v = *(const float4*)(x + (size_t)row * 256 + k4);
    ushort4 hi, lo;
    bsplit(v.x, hi.x, lo.x); bsplit(v.y, hi.y, lo.y);
    bsplit(v.z, hi.z, lo.z); bsplit(v.w, hi.w, lo.w);
    ushort* d = A3 + (size_t)row * 512 + k4;
    *(ushort4*)(d)       = hi;
    *(ushort4*)(d + 256) = lo;
}

// WS[n][k'] n-major, k' = [Wh | Wlo | Wh]
__global__ void wprep_all_kernel(
    const float* __restrict__ w1l, const float* __restrict__ w1r,
    const float* __restrict__ w2l, const float* __restrict__ w2r,
    const float* __restrict__ w3l, const float* __restrict__ w3r,
    const float* __restrict__ dw1,
    ushort* __restrict__ WS1, ushort* __restrict__ WS2,
    ushort* __restrict__ WS3, ushort* __restrict__ WS4)
{
    int which = blockIdx.y;
    int n = blockIdx.x;
    int k = threadIdx.x;
    const float *wa, *wb;
    int K, lda, aoff, boff;
    ushort* WS;
    switch (which) {
        case 0:  wa = w1l; wb = w1r; K = 256; lda = 256; aoff = 0; boff = 0;   WS = WS1; break;
        case 1:  wa = w2l; wb = w2r; K = 128; lda = 128; aoff = 0; boff = 0;   WS = WS2; break;
        case 2:  wa = w3l; wb = w3r; K = 128; lda = 128; aoff = 0; boff = 0;   WS = WS3; break;
        default: wa = dw1; wb = dw1; K = 128; lda = 256; aoff = 0; boff = 128; WS = WS4; break;
    }
    if (k >= K) return;
    const float* srcr = (n < 128) ? (wa + (size_t)n * lda + aoff)
                                  : (wb + (size_t)(n - 128) * lda + boff);
    ushort hi, lo;
    bsplit(srcr[k], hi, lo);
    ushort* d = WS + (size_t)n * 3 * K;
    d[k] = hi; d[K + k] = lo; d[2 * K + k] = hi;
}

// ---------------- MFMA GEMM ----------------
// Block = 128 rows x 256 cols (full fused output). 4 waves, each 64x128.
// A[M][KP] = [hi|lo]; W[256][KP*3/2] = [Wh|Wlo|Wh].
// K-step s: as = (s < KP/128) ? s : s - KP/128
//   s in [0,K/64)        : Ah x Wh
//   s in [K/64,2K/64)    : Ah x Wlo
//   s in [2K/64,3K/64)   : Alo x Wh
// Swizzled LDS: chunk ^ (row&7) on both write and read (same involution).
template <int KP>
__global__ __launch_bounds__(256, 2) void mm_kernel(const ushort* __restrict__ A,
                                                    const ushort* __restrict__ WS,
                                                    float* __restrict__ Cl,
                                                    float* __restrict__ Cr, int M) {
    constexpr int KS  = (KP / 64) + (KP / 128);   // 12 (KP=512) or 6 (KP=256)
    constexpr int WKP = KP + KP / 2;
    __shared__ ushort At[128 * 64];
    __shared__ ushort Bt[256 * 64];
    const int t = threadIdx.x;
    const int lane = t & 63;
    const int wave = t >> 6;
    const int wm = wave >> 1, wn = wave & 1;      // 2 row-halves x 2 col-halves
    const int row0 = blockIdx.x * 128;
    const int l15 = lane & 15;
    const int l4 = lane >> 4;
    const int arow = t >> 1;                      // A stage: row 0..127
    const int acol = (t & 1) * 32;                // col-half (bf16 units)
    const int brow = t;                           // B stage: row 0..255

    f32x4 acc[4][8] = {};

    for (int s = 0; s < KS; ++s) {
        const int as = (s < KP / 128) ? s : s - (KP / 128);   // FIXED
        // ---- stage A (16KB) + B (32KB), swizzled writes
        {
            const ushort* ga = A + (size_t)(row0 + arow) * KP + as * 64 + acol;
            ushort* la = &At[arow * 64];
            #pragma unroll
            for (int c = 0; c < 4; ++c) {
                int off = ((acol >> 3) + c) * 8;          // 16B chunk, ushort units
                off = off ^ ((arow & 7) * 8);
                *(s16x8*)(la + off) = *(const s16x8*)(ga + c * 8);
            }
            const ushort* gb = WS + (size_t)brow * WKP + s * 64;
            ushort* lb = &Bt[brow * 64];
            #pragma unroll
            for (int c = 0; c < 8; ++c) {
                int off = (c * 8) ^ ((brow & 7) * 8);
                *(s16x8*)(lb + off) = *(const s16x8*)(gb + c * 8);
            }
        }
        __syncthreads();
        #pragma unroll
        for (int kk = 0; kk < 64; kk += 32) {
            s16x8 af[4], bf[8];
            #pragma unroll
            for (int mi = 0; mi < 4; ++mi) {
                int r = wm * 64 + mi * 16 + l15;
                int off = (kk + l4 * 8) ^ ((r & 7) * 8);
                af[mi] = *(const s16x8*)&At[r * 64 + off];
            }
            #pragma unroll
            for (int ni = 0; ni < 8; ++ni) {
                int r = wn * 128 + ni * 16 + l15;
                int off = (kk + l4 * 8) ^ ((r & 7) * 8);
                bf[ni] = *(const s16x8*)&Bt[r * 64 + off];
            }
            #pragma unroll
            for (int mi = 0; mi < 4; ++mi)
                #pragma unroll
                for (int ni = 0; ni < 8; ++ni)
                    acc[mi][ni] = __builtin_amdgcn_mfma_f32_16x16x32_bf16(
                        af[mi], bf[ni], acc[mi][ni], 0, 0, 0);
        }
        __syncthreads();
    }
    // ---- epilogue: row = (lane>>4)*4+j, col = lane&15 within 16x16
    float* base = (wn == 0) ? Cl : Cr;
    #pragma unroll
    for (int mi = 0; mi < 4; ++mi) {
        int rbase = row0 + wm * 64 + mi * 16 + l4 * 4;
        #pragma unroll
        for (int ni = 0; ni < 8; ++ni) {
            int col = ni * 16 + l15;
            #pragma unroll
            for (int j = 0; j < 4; ++j) {
                int r = rbase + j;
                if (r < M) base[(size_t)r * 128 + col] = acc[mi][ni][j];
            }
        }
    }
}

// ---------------- aggregation ----------------
// out = opt_bn_relu( mean tl[src] + bl + tr[i] ), emits h[n][256] = [hi|lo]
__global__ __launch_bounds__(256) void agg_kernel(
    const float* __restrict__ tl, const float* __restrict__ tr,
    const int* __restrict__ ptr, const int* __restrict__ edges,
    const float* __restrict__ bl,
    const float* __restrict__ bng, const float* __restrict__ bnb,
    const float* __restrict__ bnm, const float* __restrict__ bnv,
    int do_bn, ushort* __restrict__ h3, int n) {
    int node = blockIdx.x * 8 + (threadIdx.x >> 5);
    if (node >= n) return;
    int q4 = (threadIdx.x & 31) << 2;             // 4 feats per thread
    int p0 = ptr[node], p1 = ptr[node + 1];
    float4 a0 = make_float4(0.f, 0.f, 0.f, 0.f), a1 = a0, a2 = a0, a3 = a0;
    float4 a4 = a0, a5 = a0, a6 = a0, a7 = a0;
    int e = p0;
    for (; e + 8 <= p1; e += 8) {
        int i0 = edges[e],     i1 = edges[e + 1], i2 = edges[e + 2], i3 = edges[e + 3];
        int i4 = edges[e + 4], i5 = edges[e + 5], i6 = edges[e + 6], i7 = edges[e + 7];
        float4 v0 = *(const float4*)(tl + (size_t)i0 * 128 + q4);
        float4 v1 = *(const float4*)(tl + (size_t)i1 * 128 + q4);
        float4 v2 = *(const float4*)(tl + (size_t)i2 * 128 + q4);
        float4 v3 = *(const float4*)(tl + (size_t)i3 * 128 + q4);
        float4 v4 = *(const float4*)(tl + (size_t)i4 * 128 + q4);
        float4 v5 = *(const float4*)(tl + (size_t)i5 * 128 + q4);
        float4 v6 = *(const float4*)(tl + (size_t)i6 * 128 + q4);
        float4 v7 = *(const float4*)(tl + (size_t)i7 * 128 + q4);
        a0.x += v0.x; a0.y += v0.y; a0.z += v0.z; a0.w += v0.w;
        a1.x += v1.x; a1.y += v1.y; a1.z += v1.z; a1.w += v1.w;
        a2.x += v2.x; a2.y += v2.y; a2.z += v2.z; a2.w += v2.w;
        a3.x += v3.x; a3.y += v3.y; a3.z += v3.z; a3.w += v3.w;
        a4.x += v4.x; a4.y += v4.y; a4.z += v4.z; a4.w += v4.w;
        a5.x += v5.x; a5.y += v5.y; a5.z += v5.z; a5.w += v5.w;
        a6.x += v6.x; a6.y += v6.y; a6.z += v6.z; a6.w += v6.w;
        a7.x += v7.x; a7.y += v7.y; a7.z += v7.z; a7.w += v7.w;
    }
    for (; e + 2 <= p1; e += 2) {
        int i0 = edges[e], i1 = edges[e + 1];
        float4 v0 = *(const float4*)(tl + (size_t)i0 * 128 + q4);
        float4 v1 = *(const float4*)(tl + (size_t)i1 * 128 + q4);
        a0.x += v0.x; a0.y += v0.y; a0.z += v0.z; a0.w += v0.w;
        a1.x += v1.x; a1.y += v1.y; a1.z += v1.z; a1.w += v1.w;
    }
    if (e < p1) {
        int i0 = edges[e];
        float4 v0 = *(const float4*)(tl + (size_t)i0 * 128 + q4);
        a2.x += v0.x; a2.y += v0.y; a2.z += v0.z; a2.w += v0.w;
    }
    float4 s;
    s.x = ((a0.x + a1.x) + (a2.x + a3.x)) + ((a4.x + a5.x) + (a6.x + a7.x));
    s.y = ((a0.y + a1.y) + (a2.y + a3.y)) + ((a4.y + a5.y) + (a6.y + a7.y));
    s.z = ((a0.z + a1.z) + (a2.z + a3.z)) + ((a4.z + a5.z) + (a6.z + a7.z));
    s.w = ((a0.w + a1.w) + (a2.w + a3.w)) + ((a4.w + a5.w) + (a6.w + a7.w));
    float inv = 1.f / fmaxf((float)(p1 - p0), 1.f);
    float4 r = *(const float4*)(tr + (size_t)node * 128 + q4);
    float4 b = *(const float4*)(bl + q4);
    float4 val;
    val.x = fmaf(s.x, inv, b.x) + r.x;
    val.y = fmaf(s.y, inv, b.y) + r.y;
    val.z = fmaf(s.z, inv, b.z) + r.z;
    val.w = fmaf(s.w, inv, b.w) + r.w;
    if (do_bn) {
        float4 g = *(const float4*)(bng + q4);
        float4 be = *(const float4*)(bnb + q4);
        float4 m = *(const float4*)(bnm + q4);
        float4 vv = *(const float4*)(bnv + q4);
        val.x = fmaxf(fmaf(val.x - m.x, g.x * rsqrtf(vv.x + 1e-5f), be.x), 0.f);
        val.y = fmaxf(fmaf(val.y - m.y, g.y * rsqrtf(vv.y + 1e-5f), be.y), 0.f);
        val.z = fmaxf(fmaf(val.z - m.z, g.z * rsqrtf(vv.z + 1e-5f), be.z), 0.f);
        val.w = fmaxf(fmaf(val.w - m.w, g.w * rsqrtf(vv.w + 1e-5f), be.w), 0.f);
    }
    ushort4 hi, lo;
    bsplit(val.x, hi.x, lo.x); bsplit(val.y, hi.y, lo.y);
    bsplit(val.z, hi.z, lo.z); bsplit(val.w, hi.w, lo.w);
    ushort* d = h3 + (size_t)node * 256 + q4;
    *(ushort4*)(d)       = hi;
    *(ushort4*)(d + 128) = lo;
}

// ---------------- decoder: relu(u[s] + v[d] + b) . w2 + b2 ----------------
__global__ __launch_bounds__(256) void decode_kernel(
    const float* __restrict__ u, const float* __restrict__ v,
    const int* __restrict__ eli, const float* __restrict__ db1,
    const float* __restrict__ dw2, const float* __restrict__ db2,
    float* __restrict__ out, int L) {
    __shared__ float sb[128], sw[128];
    if (threadIdx.x < 128) {
        sb[threadIdx.x] = db1[threadIdx.x];
        sw[threadIdx.x] = dw2[threadIdx.x];
    }
    __syncthreads();
    int p = blockIdx.x * 256 + threadIdx.x;
    if (p >= L) return;
    int s = eli[p], d = eli[L + p];
    const float* up = u + (size_t)s * 128;
    const float* vp = v + (size_t)d * 128;
    float acc = db2[0];
    #pragma unroll 8
    for (int o = 0; o < 128; o += 4) {
        float4 a = *(const float4*)(up + o);
        float4 b = *(const float4*)(vp + o);
        float4 bb = *(const float4*)(&sb[o]);
        float4 w = *(const float4*)(&sw[o]);
        acc += fmaxf(a.x + b.x + bb.x, 0.f) * w.x;
        acc += fmaxf(a.y + b.y + bb.y, 0.f) * w.y;
        acc += fmaxf(a.z + b.z + bb.z, 0.f) * w.z;
        acc += fmaxf(a.w + b.w + bb.w, 0.f) * w.w;
    }
    out[p] = acc;
}

extern "C" void kernel_launch(void* const* d_in, const int* in_sizes, int n_in,
                              void* d_out, int out_size, void* d_ws, size_t ws_size,
                              hipStream_t stream) {
    const float* x    = (const float*)d_in[0];
    const int*   ei   = (const int*)d_in[1];
    const int*   eli  = (const int*)d_in[2];
    const float* w1l  = (const float*)d_in[3];
    const float* b1l  = (const float*)d_in[4];
    const float* w1r  = (const float*)d_in[5];
    const float* w2l  = (const float*)d_in[6];
    const float* b2l  = (const float*)d_in[7];
    const float* w2r  = (const float*)d_in[8];
    const float* w3l  = (const float*)d_in[9];
    const float* b3l  = (const float*)d_in[10];
    const float* w3r  = (const float*)d_in[11];
    const float* bn1g = (const float*)d_in[12];
    const float* bn1b = (const float*)d_in[13];
    const float* bn1m = (const float*)d_in[14];
    const float* bn1v = (const float*)d_in[15];
    const float* bn2g = (const float*)d_in[16];
    const float* bn2b = (const float*)d_in[17];
    const float* bn2m = (const float*)d_in[18];
    const float* bn2v = (const float*)d_in[19];
    const float* dw1  = (const float*)d_in[20];
    const float* db1  = (const float*)d_in[21];
    const float* dw2  = (const float*)d_in[22];
    const float* db2  = (const float*)d_in[23];
    float* out = (float*)d_out;

    const int N = in_sizes[0] / 256;
    const int E = in_sizes[1] / 2;
    const int L = in_sizes[2] / 2;
    const int* src = ei;
    const int* dst = ei + E;
    const int ntiles = (N + 1023) >> 10;
    const int nblk = (N + 127) / 128;
    const int Npad = nblk * 128;

    char* wsb = (char*)d_ws;
    size_t off = 0;
    auto carve = [&](size_t bytes) -> void* {
        void* p = wsb + off;
        off += (bytes + 255) & ~(size_t)255;
        return p;
    };
    int* ptr        = (int*)carve((size_t)(N + 1) * 4);
    int* cursor     = (int*)carve((size_t)N * 4);
    int* tilesum    = (int*)carve((size_t)ntiles * 4);
    int* edges      = (int*)carve((size_t)E * 4);
    ushort* WS1     = (ushort*)carve((size_t)256 * 768 * 2);
    ushort* WS2     = (ushort*)carve((size_t)256 * 384 * 2);
    ushort* WS3     = (ushort*)carve((size_t)256 * 384 * 2);
    ushort* WS4     = (ushort*)carve((size_t)256 * 384 * 2);
    float* tl_c     = (float*)carve((size_t)N * 128 * 4);    // neighbor-transform
    float* tr_c     = (float*)carve((size_t)N * 128 * 4);    // root-transform
    ushort* A3      = (ushort*)carve((size_t)Npad * 512 * 2); // layer-1 [hi|lo]
    ushort* h3      = A3;                                     // reuse: [Npad][256]

    // ---- CSR build ----
    hipMemsetAsync(cursor, 0, (size_t)N * 4, stream);
    count_kernel<<<(E + 255) / 256, 256, 0, stream>>>(dst, cursor, E);
    scanA_kernel<<<ntiles, 1024, 0, stream>>>(cursor, ptr, tilesum, N);
    scanB_kernel<<<1, 64, 0, stream>>>(tilesum, ptr, ntiles, N);
    scanC_kernel<<<(N + 255) / 256, 256, 0, stream>>>(ptr, tilesum, N);
    hipMemsetAsync(cursor, 0, (size_t)N * 4, stream);
    scatter_kernel<<<(E + 255) / 256, 256, 0, stream>>>(src, dst, ptr, cursor, edges, E);

    // ---- conversions ----
    convx_kernel<<<(N * 64 + 255) / 256, 256, 0, stream>>>(x, A3, N * 64);
    wprep_all_kernel<<<dim3(256, 4), 256, 0, stream>>>(w1l, w1r, w2l, w2r, w3l, w3r,
                                                       dw1, WS1, WS2, WS3, WS4);

    // ---- layer 1 ----
    mm_kernel<512><<<nblk, 256, 0, stream>>>(A3, WS1, tl_c, tr_c, N);
    agg_kernel<<<(N + 7) / 8, 256, 0, stream>>>(tl_c, tr_c, ptr, edges, b1l,
                                                bn1g, bn1b, bn1m, bn1v, 1, h3, N);
    // ---- layer 2 ----
    mm_kernel<256><<<nblk, 256, 0, stream>>>(h3, WS2, tl_c, tr_c, N);
    agg_kernel<<<(N + 7) / 8, 256, 0, stream>>>(tl_c, tr_c, ptr, edges, b2l,
                                                bn2g, bn2b, bn2m, bn2v, 1, h3, N);
    // ---- layer 3 (no BN) ----
    mm_kernel<256><<<nblk, 256, 0, stream>>>(h3, WS3, tl_c, tr_c, N);
    agg_kernel<<<(N + 7) / 8, 256, 0, stream>>>(tl_c, tr_c, ptr, edges, b3l,
                                                bn1g, bn1b, bn1m, bn1v, 0, h3, N);
    // ---- decoder transforms u|v, then pair decode ----
    mm_kernel<256><<<nblk, 256, 0, stream>>>(h3, WS4, tl_c, tr_c, N);
    decode_kernel<<<(L + 255) / 256, 256, 0, stream>>>(tl_c, tr_c, eli, db1, dw2, db2, out, L);
}

// Round 6
// 452.817 us; speedup vs baseline: 2.6681x; 1.0105x over previous
//
#include <hip/hip_runtime.h>

// ---------------------------------------------------------------------------
// GraphSAGE (3x SAGEConv mean-agg + BN/ReLU) + link decoder.
// R6 changes vs R5:
//  - mm: global_load_lds (16B) staging, LINEAR LDS dest; producers store A/W
//    PRE-SWIZZLED (chunk c at c^(row&7) within each 64-ushort K-slice) so the
//    ds_read XOR (unchanged) sees the same involution. No reg-staging.
//  - agg: one node per WAVE (even/odd edge slots per half, __shfl_xor(32)
//    combine -> no divergence), 8-deep unroll with __launch_bounds__(256,4)
//    so the unroll actually fits in registers (R5: VGPR=36 serialized it).
// ---------------------------------------------------------------------------

typedef unsigned int uint;
using s16x8 = __attribute__((ext_vector_type(8))) short;
using f32x4 = __attribute__((ext_vector_type(4))) float;

__device__ inline void bsplit(float v, ushort& hi, ushort& lo) {
    // round-to-nearest-even bf16 split: v ~= hi + lo to ~2^-17 rel
    uint u = __float_as_uint(v);
    uint hb = (u + 0x7FFFu + ((u >> 16) & 1u)) >> 16;
    hi = (ushort)hb;
    float r = v - __uint_as_float(hb << 16);
    uint u2 = __float_as_uint(r);
    lo = (ushort)((u2 + 0x7FFFu + ((u2 >> 16) & 1u)) >> 16);
}

// swizzle a ushort index within its 64-ushort K-slice: chunk ^= (row&7)
__device__ inline uint swz(uint i, uint r) {
    return (i & ~63u) | ((i ^ (r << 3)) & 56u) | (i & 7u);
}

// async global->LDS, 16 bytes per lane
__device__ inline void gload16(const void* g, void* l) {
    __builtin_amdgcn_global_load_lds(
        (const __attribute__((address_space(1))) unsigned int*)g,
        (__attribute__((address_space(3))) unsigned int*)l, 16, 0, 0);
}

// ---------------- CSR build ----------------
__global__ void count_kernel(const int* __restrict__ dst, int* __restrict__ cnt, int E) {
    int i = blockIdx.x * blockDim.x + threadIdx.x;
    if (i < E) atomicAdd(&cnt[dst[i]], 1);
}

__global__ void scanA_kernel(const int* __restrict__ cnt, int* __restrict__ ptr,
                             int* __restrict__ tilesum, int n) {
    __shared__ int sd[1024];
    int t = threadIdx.x;
    int i = blockIdx.x * 1024 + t;
    int v = (i < n) ? cnt[i] : 0;
    sd[t] = v;
    __syncthreads();
    #pragma unroll
    for (int off = 1; off < 1024; off <<= 1) {
        int add = (t >= off) ? sd[t - off] : 0;
        __syncthreads();
        sd[t] += add;
        __syncthreads();
    }
    if (i < n) ptr[i] = sd[t] - v;              // local exclusive
    if (t == 1023) tilesum[blockIdx.x] = sd[t]; // tile total
}

__global__ void scanB_kernel(int* __restrict__ tilesum, int* __restrict__ ptr,
                             int ntiles, int n) {
    if (threadIdx.x == 0 && blockIdx.x == 0) {
        int running = 0;
        for (int b = 0; b < ntiles; ++b) {
            int t = tilesum[b];
            tilesum[b] = running;
            running += t;
        }
        ptr[n] = running;
    }
}

__global__ void scanC_kernel(int* __restrict__ ptr, const int* __restrict__ tilesum, int n) {
    int i = blockIdx.x * blockDim.x + threadIdx.x;
    if (i < n) ptr[i] += tilesum[i >> 10];
}

__global__ void scatter_kernel(const int* __restrict__ src, const int* __restrict__ dst,
                               const int* __restrict__ ptr, int* __restrict__ cursor,
                               int* __restrict__ edges, int E) {
    int i = blockIdx.x * blockDim.x + threadIdx.x;
    if (i < E) {
        int d = dst[i];
        int pos = ptr[d] + atomicAdd(&cursor[d], 1);
        edges[pos] = src[i];
    }
}

// ---------------- conversions (pre-swizzled stores) ----------------
// A row (K=256): [hi(0..255) | lo(0..255)] (KP=512), chunk-swizzled per slice
__global__ __launch_bounds__(256) void convx_kernel(const float* __restrict__ x,
                                                    ushort* __restrict__ A3, int total) {
    int e = blockIdx.x * 256 + threadIdx.x;   // total = N*64 (float4 groups)
    if (e >= total) return;
    uint row = e >> 6;
    uint k4 = (e & 63) << 2;
    float4 v = *(const float4*)(x + (size_t)row * 256 + k4);
    ushort4 hi, lo;
    bsplit(v.x, hi.x, lo.x); bsplit(v.y, hi.y, lo.y);
    bsplit(v.z, hi.z, lo.z); bsplit(v.w, hi.w, lo.w);
    ushort* d = A3 + (size_t)row * 512;
    *(ushort4*)(d + swz(k4, row))       = hi;
    *(ushort4*)(d + swz(k4 + 256, row)) = lo;
}

// WS[n][k'] n-major, k' = [Wh | Wlo | Wh], chunk-swizzled per slice
__global__ void wprep_all_kernel(
    const float* __restrict__ w1l, const float* __restrict__ w1r,
    const float* __restrict__ w2l, const float* __restrict__ w2r,
    const float* __restrict__ w3l, const float* __restrict__ w3r,
    const float* __restrict__ dw1,
    ushort* __restrict__ WS1, ushort* __restrict__ WS2,
    ushort* __restrict__ WS3, ushort* __restrict__ WS4)
{
    int which = blockIdx.y;
    uint n = blockIdx.x;
    uint k = threadIdx.x;
    const float *wa, *wb;
    uint K, lda, aoff, boff;
    ushort* WS;
    switch (which) {
        case 0:  wa = w1l; wb = w1r; K = 256; lda = 256; aoff = 0; boff = 0;   WS = WS1; break;
        case 1:  wa = w2l; wb = w2r; K = 128; lda = 128; aoff = 0; boff = 0;   WS = WS2; break;
        case 2:  wa = w3l; wb = w3r; K = 128; lda = 128; aoff = 0; boff = 0;   WS = WS3; break;
        default: wa = dw1; wb = dw1; K = 128; lda = 256; aoff = 0; boff = 128; WS = WS4; break;
    }
    if (k >= K) return;
    const float* srcr = (n < 128) ? (wa + (size_t)n * lda + aoff)
                                  : (wb + (size_t)(n - 128) * lda + boff);
    ushort hi, lo;
    bsplit(srcr[k], hi, lo);
    ushort* d = WS + (size_t)n * 3 * K;
    d[swz(k, n)]         = hi;
    d[swz(K + k, n)]     = lo;
    d[swz(2 * K + k, n)] = hi;
}

// ---------------- MFMA GEMM ----------------
// Block = 128 rows x 256 cols. 4 waves, each 64x128.
// A[M][KP] = [hi|lo] pre-swizzled; W[256][KP*3/2] = [Wh|Wlo|Wh] pre-swizzled.
// Staging = global_load_lds 16B, linear LDS; ds_read applies the XOR.
// K-step s: as = (s < KP/128) ? s : s - KP/128
template <int KP>
__global__ __launch_bounds__(256, 2) void mm_kernel(const ushort* __restrict__ A,
                                                    const ushort* __restrict__ WS,
                                                    float* __restrict__ Cl,
                                                    float* __restrict__ Cr, int M) {
    constexpr int KS  = (KP / 64) + (KP / 128);   // 12 (KP=512) or 6 (KP=256)
    constexpr int WKP = KP + KP / 2;
    __shared__ ushort At[128 * 64];
    __shared__ ushort Bt[256 * 64];
    const int t = threadIdx.x;
    const int lane = t & 63;
    const int wave = t >> 6;
    const int wm = wave >> 1, wn = wave & 1;      // 2 row-halves x 2 col-halves
    const int row0 = blockIdx.x * 128;
    const int l15 = lane & 15;
    const int l4 = lane >> 4;
    const int l8 = lane >> 3;                     // staging: row within 8-row group
    const int c8 = lane & 7;                      // staging: chunk within row

    f32x4 acc[4][8] = {};

    for (int s = 0; s < KS; ++s) {
        const int as = (s < KP / 128) ? s : s - (KP / 128);
        // ---- stage A (16KB, 16 calls) + B (32KB, 32 calls), linear LDS dest
        #pragma unroll
        for (int j = 0; j < 4; ++j) {
            int jj = wave + j * 4;                // A group 0..15
            int r = jj * 8 + l8;
            const ushort* ga = A + (size_t)(row0 + r) * KP + as * 64 + c8 * 8;
            gload16(ga, (char*)At + jj * 1024 + lane * 16);
        }
        #pragma unroll
        for (int j = 0; j < 8; ++j) {
            int jj = wave + j * 4;                // B group 0..31
            int r = jj * 8 + l8;
            const ushort* gb = WS + (size_t)r * WKP + s * 64 + c8 * 8;
            gload16(gb, (char*)Bt + jj * 1024 + lane * 16);
        }
        __syncthreads();
        #pragma unroll
        for (int kk = 0; kk < 64; kk += 32) {
            s16x8 af[4], bf[8];
            #pragma unroll
            for (int mi = 0; mi < 4; ++mi) {
                int r = wm * 64 + mi * 16 + l15;
                int off = (kk + l4 * 8) ^ ((r & 7) * 8);
                af[mi] = *(const s16x8*)&At[r * 64 + off];
            }
            #pragma unroll
            for (int ni = 0; ni < 8; ++ni) {
                int r = wn * 128 + ni * 16 + l15;
                int off = (kk + l4 * 8) ^ ((r & 7) * 8);
                bf[ni] = *(const s16x8*)&Bt[r * 64 + off];
            }
            #pragma unroll
            for (int mi = 0; mi < 4; ++mi)
                #pragma unroll
                for (int ni = 0; ni < 8; ++ni)
                    acc[mi][ni] = __builtin_amdgcn_mfma_f32_16x16x32_bf16(
                        af[mi], bf[ni], acc[mi][ni], 0, 0, 0);
        }
        __syncthreads();
    }
    // ---- epilogue: row = (lane>>4)*4+j, col = lane&15 within 16x16
    float* base = (wn == 0) ? Cl : Cr;
    #pragma unroll
    for (int mi = 0; mi < 4; ++mi) {
        int rbase = row0 + wm * 64 + mi * 16 + l4 * 4;
        #pragma unroll
        for (int ni = 0; ni < 8; ++ni) {
            int col = ni * 16 + l15;
            #pragma unroll
            for (int j = 0; j < 4; ++j) {
                int r = rbase + j;
                if (r < M) base[(size_t)r * 128 + col] = acc[mi][ni][j];
            }
        }
    }
}

// ---------------- aggregation ----------------
// One node per wave: lanes 0-31 even edge slots, 32-63 odd; shfl_xor combine.
// out = opt_bn_relu( mean tl[src] + bl + tr[i] ), emits h[n][256]=[hi|lo] swz.
__global__ __launch_bounds__(256, 4) void agg_kernel(
    const float* __restrict__ tl, const float* __restrict__ tr,
    const int* __restrict__ ptr, const int* __restrict__ edges,
    const float* __restrict__ bl,
    const float* __restrict__ bng, const float* __restrict__ bnb,
    const float* __restrict__ bnm, const float* __restrict__ bnv,
    int do_bn, ushort* __restrict__ h3, int n) {
    const int wave = threadIdx.x >> 6;
    const int lane = threadIdx.x & 63;
    const uint node = blockIdx.x * 4 + wave;
    if (node >= (uint)n) return;
    const int half = lane >> 5;
    const uint q4 = (lane & 31) << 2;             // 4 feats per lane
    const int p0 = ptr[node], p1 = ptr[node + 1];
    float4 a0 = make_float4(0.f, 0.f, 0.f, 0.f), a1 = a0, a2 = a0, a3 = a0;
    float4 a4 = a0, a5 = a0, a6 = a0, a7 = a0;
    int e = p0 + half;
    for (; e + 14 < p1; e += 16) {                // 8 edges per half per iter
        int i0 = edges[e],      i1 = edges[e + 2],  i2 = edges[e + 4],  i3 = edges[e + 6];
        int i4 = edges[e + 8],  i5 = edges[e + 10], i6 = edges[e + 12], i7 = edges[e + 14];
        float4 v0 = *(const float4*)(tl + (size_t)i0 * 128 + q4);
        float4 v1 = *(const float4*)(tl + (size_t)i1 * 128 + q4);
        float4 v2 = *(const float4*)(tl + (size_t)i2 * 128 + q4);
        float4 v3 = *(const float4*)(tl + (size_t)i3 * 128 + q4);
        float4 v4 = *(const float4*)(tl + (size_t)i4 * 128 + q4);
        float4 v5 = *(const float4*)(tl + (size_t)i5 * 128 + q4);
        float4 v6 = *(const float4*)(tl + (size_t)i6 * 128 + q4);
        float4 v7 = *(const float4*)(tl + (size_t)i7 * 128 + q4);
        a0.x += v0.x; a0.y += v0.y; a0.z += v0.z; a0.w += v0.w;
        a1.x += v1.x; a1.y += v1.y; a1.z += v1.z; a1.w += v1.w;
        a2.x += v2.x; a2.y += v2.y; a2.z += v2.z; a2.w += v2.w;
        a3.x += v3.x; a3.y += v3.y; a3.z += v3.z; a3.w += v3.w;
        a4.x += v4.x; a4.y += v4.y; a4.z += v4.z; a4.w += v4.w;
        a5.x += v5.x; a5.y += v5.y; a5.z += v5.z; a5.w += v5.w;
        a6.x += v6.x; a6.y += v6.y; a6.z += v6.z; a6.w += v6.w;
        a7.x += v7.x; a7.y += v7.y; a7.z += v7.z; a7.w += v7.w;
    }
    for (; e < p1; e += 2) {
        int i0 = edges[e];
        float4 v0 = *(const float4*)(tl + (size_t)i0 * 128 + q4);
        a0.x += v0.x; a0.y += v0.y; a0.z += v0.z; a0.w += v0.w;
    }
    float4 s;
    s.x = ((a0.x + a1.x) + (a2.x + a3.x)) + ((a4.x + a5.x) + (a6.x + a7.x));
    s.y = ((a0.y + a1.y) + (a2.y + a3.y)) + ((a4.y + a5.y) + (a6.y + a7.y));
    s.z = ((a0.z + a1.z) + (a2.z + a3.z)) + ((a4.z + a5.z) + (a6.z + a7.z));
    s.w = ((a0.w + a1.w) + (a2.w + a3.w)) + ((a4.w + a5.w) + (a6.w + a7.w));
    // combine even/odd halves (lane <-> lane^32)
    s.x += __shfl_xor(s.x, 32);
    s.y += __shfl_xor(s.y, 32);
    s.z += __shfl_xor(s.z, 32);
    s.w += __shfl_xor(s.w, 32);
    if (half == 0) {
        float inv = 1.f / fmaxf((float)(p1 - p0), 1.f);
        float4 r = *(const float4*)(tr + (size_t)node * 128 + q4);
        float4 b = *(const float4*)(bl + q4);
        float4 val;
        val.x = fmaf(s.x, inv, b.x) + r.x;
        val.y = fmaf(s.y, inv, b.y) + r.y;
        val.z = fmaf(s.z, inv, b.z) + r.z;
        val.w = fmaf(s.w, inv, b.w) + r.w;
        if (do_bn) {
            float4 g = *(const float4*)(bng + q4);
            float4 be = *(const float4*)(bnb + q4);
            float4 m = *(const float4*)(bnm + q4);
            float4 vv = *(const float4*)(bnv + q4);
            val.x = fmaxf(fmaf(val.x - m.x, g.x * rsqrtf(vv.x + 1e-5f), be.x), 0.f);
            val.y = fmaxf(fmaf(val.y - m.y, g.y * rsqrtf(vv.y + 1e-5f), be.y), 0.f);
            val.z = fmaxf(fmaf(val.z - m.z, g.z * rsqrtf(vv.z + 1e-5f), be.z), 0.f);
            val.w = fmaxf(fmaf(val.w - m.w, g.w * rsqrtf(vv.w + 1e-5f), be.w), 0.f);
        }
        ushort4 hi, lo;
        bsplit(val.x, hi.x, lo.x); bsplit(val.y, hi.y, lo.y);
        bsplit(val.z, hi.z, lo.z); bsplit(val.w, hi.w, lo.w);
        ushort* d = h3 + (size_t)node * 256;
        *(ushort4*)(d + swz(q4, node))       = hi;
        *(ushort4*)(d + swz(q4 + 128, node)) = lo;
    }
}

// ---------------- decoder: relu(u[s] + v[d] + b) . w2 + b2 ----------------
__global__ __launch_bounds__(256) void decode_kernel(
    const float* __restrict__ u, const float* __restrict__ v,
    const int* __restrict__ eli, const float* __restrict__ db1,
    const float* __restrict__ dw2, const float* __restrict__ db2,
    float* __restrict__ out, int L) {
    __shared__ float sb[128], sw[128];
    if (threadIdx.x < 128) {
        sb[threadIdx.x] = db1[threadIdx.x];
        sw[threadIdx.x] = dw2[threadIdx.x];
    }
    __syncthreads();
    int p = blockIdx.x * 256 + threadIdx.x;
    if (p >= L) return;
    int s = eli[p], d = eli[L + p];
    const float* up = u + (size_t)s * 128;
    const float* vp = v + (size_t)d * 128;
    float acc = db2[0];
    #pragma unroll 8
    for (int o = 0; o < 128; o += 4) {
        float4 a = *(const float4*)(up + o);
        float4 b = *(const float4*)(vp + o);
        float4 bb = *(const float4*)(&sb[o]);
        float4 w = *(const float4*)(&sw[o]);
        acc += fmaxf(a.x + b.x + bb.x, 0.f) * w.x;
        acc += fmaxf(a.y + b.y + bb.y, 0.f) * w.y;
        acc += fmaxf(a.z + b.z + bb.z, 0.f) * w.z;
        acc += fmaxf(a.w + b.w + bb.w, 0.f) * w.w;
    }
    out[p] = acc;
}

extern "C" void kernel_launch(void* const* d_in, const int* in_sizes, int n_in,
                              void* d_out, int out_size, void* d_ws, size_t ws_size,
                              hipStream_t stream) {
    const float* x    = (const float*)d_in[0];
    const int*   ei   = (const int*)d_in[1];
    const int*   eli  = (const int*)d_in[2];
    const float* w1l  = (const float*)d_in[3];
    const float* b1l  = (const float*)d_in[4];
    const float* w1r  = (const float*)d_in[5];
    const float* w2l  = (const float*)d_in[6];
    const float* b2l  = (const float*)d_in[7];
    const float* w2r  = (const float*)d_in[8];
    const float* w3l  = (const float*)d_in[9];
    const float* b3l  = (const float*)d_in[10];
    const float* w3r  = (const float*)d_in[11];
    const float* bn1g = (const float*)d_in[12];
    const float* bn1b = (const float*)d_in[13];
    const float* bn1m = (const float*)d_in[14];
    const float* bn1v = (const float*)d_in[15];
    const float* bn2g = (const float*)d_in[16];
    const float* bn2b = (const float*)d_in[17];
    const float* bn2m = (const float*)d_in[18];
    const float* bn2v = (const float*)d_in[19];
    const float* dw1  = (const float*)d_in[20];
    const float* db1  = (const float*)d_in[21];
    const float* dw2  = (const float*)d_in[22];
    const float* db2  = (const float*)d_in[23];
    float* out = (float*)d_out;

    const int N = in_sizes[0] / 256;
    const int E = in_sizes[1] / 2;
    const int L = in_sizes[2] / 2;
    const int* src = ei;
    const int* dst = ei + E;
    const int ntiles = (N + 1023) >> 10;
    const int nblk = (N + 127) / 128;
    const int Npad = nblk * 128;

    char* wsb = (char*)d_ws;
    size_t off = 0;
    auto carve = [&](size_t bytes) -> void* {
        void* p = wsb + off;
        off += (bytes + 255) & ~(size_t)255;
        return p;
    };
    int* ptr        = (int*)carve((size_t)(N + 1) * 4);
    int* cursor     = (int*)carve((size_t)N * 4);
    int* tilesum    = (int*)carve((size_t)ntiles * 4);
    int* edges      = (int*)carve((size_t)E * 4);
    ushort* WS1     = (ushort*)carve((size_t)256 * 768 * 2);
    ushort* WS2     = (ushort*)carve((size_t)256 * 384 * 2);
    ushort* WS3     = (ushort*)carve((size_t)256 * 384 * 2);
    ushort* WS4     = (ushort*)carve((size_t)256 * 384 * 2);
    float* tl_c     = (float*)carve((size_t)N * 128 * 4);    // neighbor-transform
    float* tr_c     = (float*)carve((size_t)N * 128 * 4);    // root-transform
    ushort* A3      = (ushort*)carve((size_t)Npad * 512 * 2); // layer-1 [hi|lo]
    ushort* h3      = A3;                                     // reuse: [Npad][256]

    // ---- CSR build ----
    hipMemsetAsync(cursor, 0, (size_t)N * 4, stream);
    count_kernel<<<(E + 255) / 256, 256, 0, stream>>>(dst, cursor, E);
    scanA_kernel<<<ntiles, 1024, 0, stream>>>(cursor, ptr, tilesum, N);
    scanB_kernel<<<1, 64, 0, stream>>>(tilesum, ptr, ntiles, N);
    scanC_kernel<<<(N + 255) / 256, 256, 0, stream>>>(ptr, tilesum, N);
    hipMemsetAsync(cursor, 0, (size_t)N * 4, stream);
    scatter_kernel<<<(E + 255) / 256, 256, 0, stream>>>(src, dst, ptr, cursor, edges, E);

    // ---- conversions ----
    convx_kernel<<<(N * 64 + 255) / 256, 256, 0, stream>>>(x, A3, N * 64);
    wprep_all_kernel<<<dim3(256, 4), 256, 0, stream>>>(w1l, w1r, w2l, w2r, w3l, w3r,
                                                       dw1, WS1, WS2, WS3, WS4);

    // ---- layer 1 ----
    mm_kernel<512><<<nblk, 256, 0, stream>>>(A3, WS1, tl_c, tr_c, N);
    agg_kernel<<<(N + 3) / 4, 256, 0, stream>>>(tl_c, tr_c, ptr, edges, b1l,
                                                bn1g, bn1b, bn1m, bn1v, 1, h3, N);
    // ---- layer 2 ----
    mm_kernel<256><<<nblk, 256, 0, stream>>>(h3, WS2, tl_c, tr_c, N);
    agg_kernel<<<(N + 3) / 4, 256, 0, stream>>>(tl_c, tr_c, ptr, edges, b2l,
                                                bn2g, bn2b, bn2m, bn2v, 1, h3, N);
    // ---- layer 3 (no BN) ----
    mm_kernel<256><<<nblk, 256, 0, stream>>>(h3, WS3, tl_c, tr_c, N);
    agg_kernel<<<(N + 3) / 4, 256, 0, stream>>>(tl_c, tr_c, ptr, edges, b3l,
                                                bn1g, bn1b, bn1m, bn1v, 0, h3, N);
    // ---- decoder transforms u|v, then pair decode ----
    mm_kernel<256><<<nblk, 256, 0, stream>>>(h3, WS4, tl_c, tr_c, N);
    decode_kernel<<<(L + 255) / 256, 256, 0, stream>>>(tl_c, tr_c, eli, db1, dw2, db2, out, L);
}